// Round 15
// baseline (48.103 us; speedup 1.0000x reference)
//
#include <hip/hip_runtime.h>

// ResNetVQC: 6 q3-layers of 32 three-qubit circuits + linear head.
// z_w = sum_p v0[p] * ( T[w][p][.] . m[.] ),  m = 9 monomials of (c1,s1,c2,s2),
// v0 = (1, c0, s0); evaluated with v_dot2_f32_f16 (T f16, f32 accumulate).
// T pre-scaled by 1/2pi (layers 0-4) so angles flow in REVOLUTIONS.
//
// Round-15: amortize the per-layer T scalar-load convoy over 2x work.
//  * 128 rows per block (512 threads, lane b owns rows b and 64+b).
//  * per layer: 6 exchange ds_reads issued up-front, then 8 evals share ONE
//    wave-uniform T slice (tile A/B interleaved per-k so T SGPRs stay hot).
//    Post-barrier s_load stall and barrier skew per eval both halve.
//  * exchange carries PACKED (sin,cos) f16 pairs (one dword per value);
//    reader builds M0..M4 with 2 v_pk_mul_f16 + 5 shuffles.
//  * LDS row stride 100 dwords -> b128 ops at free 2 lanes/bank/phase.

#define INV2PI 0.15915494309189535f

typedef unsigned int u32;
typedef _Float16 hf2 __attribute__((ext_vector_type(2)));

#if __has_builtin(__builtin_amdgcn_fdot2)
#define HAVE_FDOT2 1
#else
#define HAVE_FDOT2 0
#endif

__device__ __forceinline__ float fdot2e(hf2 a, hf2 m, float acc) {
#if HAVE_FDOT2
  return __builtin_amdgcn_fdot2(a, m, acc, false);
#else
  return fmaf((float)a.x, (float)m.x, fmaf((float)a.y, (float)m.y, acc));
#endif
}

#if __has_builtin(__builtin_amdgcn_sinf)
__device__ __forceinline__ float hwsin(float r) { return __builtin_amdgcn_sinf(r); }
__device__ __forceinline__ float hwcos(float r) { return __builtin_amdgcn_cosf(r); }
#else
__device__ __forceinline__ float hwsin(float r) { return __sinf(r * 6.2831853071795865f); }
__device__ __forceinline__ float hwcos(float r) { return __cosf(r * 6.2831853071795865f); }
#endif

__device__ __forceinline__ hf2 pkrtz(float a, float b) {
#if __has_builtin(__builtin_amdgcn_cvt_pkrtz)
  return __builtin_bit_cast(hf2, __builtin_amdgcn_cvt_pkrtz(a, b));
#else
  hf2 v = {(_Float16)a, (_Float16)b};
  return v;
#endif
}

__device__ __forceinline__ u32 pk_sc(float hrev) {  // (sin|cos) packed dword
  return __builtin_bit_cast(u32, pkrtz(hwsin(hrev), hwcos(hrev)));
}
__device__ __forceinline__ hf2 as_hf2(u32 v) { return __builtin_bit_cast(hf2, v); }

// ---------------- setup kernel: build T (parallel: one block per (l,k)) -----
__global__ __launch_bounds__(64) void build_T(const float* __restrict__ thetas,
                                              hf2* __restrict__ Thp,
                                              hf2* __restrict__ T5) {
  const int l = blockIdx.x >> 5;
  const int k = blockIdx.x & 31;
  const int t = threadIdx.x;  // 0..63
  __shared__ float Ur[8][8], Ui[8][8];  // [col][amp]
  __shared__ float rem[3][8][8];
  __shared__ float tvs[3][27];

  // phase A: lanes 0-7 each build U column `t` (serial 54-gate circuit)
  if (t < 8) {
    const int col = t;
    float pr[8], pi[8];
#pragma unroll
    for (int j = 0; j < 8; ++j) { pr[j] = (j == col) ? 1.f : 0.f; pi[j] = 0.f; }
    const float* th = thetas + (size_t)(l * 32 + k) * 54;  // [d][w][3]
#pragma unroll
    for (int d = 0; d < 6; ++d) {
#pragma unroll
      for (int w = 0; w < 3; ++w) {
        float phi = th[(d * 3 + w) * 3 + 0];
        float tht = th[(d * 3 + w) * 3 + 1];
        float omg = th[(d * 3 + w) * 3 + 2];
        float st, ct, sp, cp, sm, cm;
        __sincosf(0.5f * tht, &st, &ct);
        __sincosf(0.5f * (phi + omg), &sp, &cp);
        __sincosf(0.5f * (phi - omg), &sm, &cm);
        float m00r =  cp * ct, m00i = -sp * ct;
        float m01r = -cm * st, m01i = -sm * st;
        float m10r =  cm * st, m10i = -sm * st;
        float m11r =  cp * ct, m11i =  sp * ct;
        const int s = 4 >> w;  // qubit0 = MSB
#pragma unroll
        for (int base = 0; base < 8; ++base) {
          if (base & s) continue;
          float ar = pr[base], ai = pi[base];
          float br = pr[base + s], bi = pi[base + s];
          pr[base]     = m00r * ar - m00i * ai + m01r * br - m01i * bi;
          pi[base]     = m00r * ai + m00i * ar + m01r * bi + m01i * br;
          pr[base + s] = m10r * ar - m10i * ai + m11r * br - m11i * bi;
          pi[base + s] = m10r * ai + m10i * ar + m11r * bi + m11i * br;
        }
      }
      const int r = (d & 1) + 1;  // CNOT ring: ranges 1,2,1,2,...
#pragma unroll
      for (int w = 0; w < 3; ++w) {
        const int cs = 4 >> w;
        const int ts = 4 >> ((w + r) % 3);
#pragma unroll
        for (int idx = 0; idx < 8; ++idx) {
          if (!(idx & cs) || (idx & ts)) continue;
          const int j2 = idx | ts;
          float tr = pr[idx]; pr[idx] = pr[j2]; pr[j2] = tr;
          float ti = pi[idx]; pi[idx] = pi[j2]; pi[j2] = ti;
        }
      }
    }
#pragma unroll
    for (int j = 0; j < 8; ++j) { Ur[col][j] = pr[j]; Ui[col][j] = pi[j]; }
  }
  __syncthreads();

  // phase B: 64 lanes: rem_w[a][b] = sum_c zs_w(c)*(U*[c,a]U[c,b]); U[c][a]=Ur[a][c]
  {
    const int a = t >> 3, bb = t & 7;
#pragma unroll
    for (int w = 0; w < 3; ++w) {
      float acc = 0.f;
#pragma unroll
      for (int c = 0; c < 8; ++c) {
        float zs = ((c >> (2 - w)) & 1) ? -1.f : 1.f;
        acc += zs * (Ur[a][c] * Ur[bb][c] + Ui[a][c] * Ui[bb][c]);
      }
      rem[w][a][bb] = acc;
    }
  }
  __syncthreads();

  // phase C: 81 tv entries (basis change to monomials)
  {
    const int   ga[3][2] = {{0, 1}, {0, 1}, {0, 1}};
    const int   gb[3][2] = {{0, 1}, {0, 1}, {1, 0}};
    const float gc[3][2] = {{0.5f, 0.5f}, {0.5f, -0.5f}, {0.5f, 0.5f}};
    const int MONO[3][3] = {{0, 3, 4}, {1, 5, 6}, {2, 7, 8}};
    for (int e = t; e < 81; e += 64) {
      int w = e / 27, re = e % 27;
      int p = re / 9, q = (re % 9) / 3, r = re % 3;
      float acc = 0.f;
#pragma unroll
      for (int e0 = 0; e0 < 2; ++e0)
#pragma unroll
        for (int e1 = 0; e1 < 2; ++e1)
#pragma unroll
          for (int e2 = 0; e2 < 2; ++e2) {
            int a  = (ga[p][e0] << 2) | (ga[q][e1] << 1) | ga[r][e2];
            int bb = (gb[p][e0] << 2) | (gb[q][e1] << 1) | gb[r][e2];
            acc += gc[p][e0] * gc[q][e1] * gc[r][e2] * rem[w][a][bb];
          }
      tvs[w][p * 9 + MONO[q][r]] = acc;
    }
  }
  __syncthreads();

  // phase D: pack to hf2 pairs. u = p*5+d: d<4 -> (2d,2d+1); d==4 -> (8, 0).
  if (l < 5) {
    if (t < 48) {
      int w = t >> 4, u = t & 15;
      hf2 v;
      if (u < 15) {
        int p = u / 5, d = u % 5;
        float lo = tvs[w][p * 9 + ((d == 4) ? 8 : 2 * d)] * INV2PI;
        float hi = (d == 4) ? 0.f : tvs[w][p * 9 + 2 * d + 1] * INV2PI;
        v = pkrtz(lo, hi);
      } else {
        v = pkrtz(0.f, 0.f);
      }
      Thp[((size_t)(l * 32 + k)) * 48 + w * 16 + u] = v;
    }
  } else {
    if (t < 16) {  // wire 0 only, unscaled
      int u = t;
      hf2 v;
      if (u < 15) {
        int p = u / 5, d = u % 5;
        float lo = tvs[0][p * 9 + ((d == 4) ? 8 : 2 * d)];
        float hi = (d == 4) ? 0.f : tvs[0][p * 9 + 2 * d + 1];
        v = pkrtz(lo, hi);
      } else {
        v = pkrtz(0.f, 0.f);
      }
      T5[k * 16 + u] = v;
    }
  }
}

// ---------------- main kernel evals ----------------
// Lean eval: inputs are packed (s,c) dwords; M built with 2 pk_mul + 5 shuffles.
// C=(s0|c0), A=(s1|c1), B=(s2|c2). T pairs: (1,c1)(s1,c2)(s2,m5)(m6,m7)(m8,0).
__device__ __forceinline__ void evalk_sc(const hf2* __restrict__ tb,
                                         u32 cw, u32 aw, u32 bw,
                                         float* __restrict__ z) {
  hf2 C = as_hf2(cw), A = as_hf2(aw), B = as_hf2(bw);
  hf2 Blo = __builtin_shufflevector(B, B, 0, 0);
  hf2 Bhi = __builtin_shufflevector(B, B, 1, 1);
  hf2 Pa = A * Blo;  // {s1*s2, c1*s2} = {m8, m6}
  hf2 Pb = A * Bhi;  // {s1*c2, c1*c2} = {m7, m5}
  const hf2 ONE2 = {(_Float16)1.0f, (_Float16)1.0f};
  const hf2 ZERO2 = {(_Float16)0.0f, (_Float16)0.0f};
  hf2 M0 = __builtin_shufflevector(ONE2, A, 0, 3);   // {1, c1}
  hf2 M1 = __builtin_shufflevector(A, B, 0, 3);      // {s1, c2}
  hf2 M2 = __builtin_shufflevector(B, Pb, 0, 3);     // {s2, m5}
  hf2 M3 = __builtin_shufflevector(Pa, Pb, 1, 2);    // {m6, m7}
  hf2 M4 = __builtin_shufflevector(Pa, ZERO2, 0, 2); // {m8, 0}
  float s0 = (float)C.x, c0 = (float)C.y;
#pragma unroll
  for (int w = 0; w < 3; ++w) {
    const hf2* tw = tb + w * 16;
    float P[3];
#pragma unroll
    for (int p = 0; p < 3; ++p) {
      const hf2* tt = tw + p * 5;
      float acc = fdot2e(tt[0], M0, 0.0f);
      acc = fdot2e(tt[1], M1, acc);
      acc = fdot2e(tt[2], M2, acc);
      acc = fdot2e(tt[3], M3, acc);
      acc = fdot2e(tt[4], M4, acc);
      P[p] = acc;
    }
    z[w] = fmaf(s0, P[2], fmaf(c0, P[1], P[0]));
  }
}

// layer-5 eval (wire 0) from f32 angles (revolutions); tb = 16 hf2.
__device__ __forceinline__ float evalk1(const hf2* __restrict__ tb,
                                        float a0, float a1, float a2) {
  float s0 = hwsin(a0), c0 = hwcos(a0);
  float s1 = hwsin(a1), c1 = hwcos(a1);
  float s2 = hwsin(a2), c2 = hwcos(a2);
  hf2 M0 = pkrtz(1.0f, c1);
  hf2 M1 = pkrtz(s1, c2);
  hf2 M2 = pkrtz(s2, c1 * c2);
  hf2 M3 = pkrtz(c1 * s2, s1 * c2);
  hf2 M4 = pkrtz(s1 * s2, 0.f);
  float P[3];
#pragma unroll
  for (int p = 0; p < 3; ++p) {
    const hf2* tt = tb + p * 5;
    float acc = fdot2e(tt[0], M0, 0.0f);
    acc = fdot2e(tt[1], M1, acc);
    acc = fdot2e(tt[2], M2, acc);
    acc = fdot2e(tt[3], M3, acc);
    acc = fdot2e(tt[4], M4, acc);
    P[p] = acc;
  }
  return fmaf(s0, P[2], fmaf(c0, P[1], P[0]));
}

// 512 threads = 8 waves; 128 rows/block; lane b owns rows b and 64+b; wave ws
// owns k in {4ws..4ws+3} for BOTH row-tiles (one T slice -> 8 evals).
// Exchange ex[128][100] dwords, packed (s,c), consumer-order slots
// (S[m] = H[3*(m%32)+m/32]); 2 barriers per layer.
__global__ __launch_bounds__(512, 4) void vqc_main(const float* __restrict__ x,
                                                   const hf2* __restrict__ Thp,
                                                   const hf2* __restrict__ T5,
                                                   const float* __restrict__ wcls,
                                                   const float* __restrict__ bcls,
                                                   float* __restrict__ out) {
  __shared__ u32 ex[128 * 100];  // 51200 B
  const int t = threadIdx.x;
  const int b = t & 63;
  const int ws = __builtin_amdgcn_readfirstlane(t >> 6);
  const size_t b0 = (size_t)blockIdx.x * 128;

  // stage: load x coalesced, sincos at stage time, pack (s,c) -> natural slots
  const float4* xv = (const float4*)(x + b0 * 96);
#pragma unroll
  for (int i = 0; i < 6; ++i) {
    int f = t + i * 512;  // float4 index in 128x96 tile (3072 total)
    float4 v = xv[f];
    int d = 4 * f, row = d / 96, col = d % 96;
    uint4 pv;
    pv.x = pk_sc(v.x * INV2PI);
    pv.y = pk_sc(v.y * INV2PI);
    pv.z = pk_sc(v.z * INV2PI);
    pv.w = pk_sc(v.w * INV2PI);
    *(uint4*)&ex[row * 100 + col] = pv;
  }
  __syncthreads();

  float hA[4][3], hB[4][3];
  const int rbA = b * 100 + 12 * ws;
  const int rbB = (64 + b) * 100 + 12 * ws;

#pragma unroll
  for (int l = 0; l < 5; ++l) {
    // issue all 6 exchange reads up-front (independent ds_read_b128s)
    uint4 a0 = *(const uint4*)&ex[rbA + 0];
    uint4 a1 = *(const uint4*)&ex[rbA + 4];
    uint4 a2 = *(const uint4*)&ex[rbA + 8];
    uint4 e0 = *(const uint4*)&ex[rbB + 0];
    uint4 e1 = *(const uint4*)&ex[rbB + 4];
    uint4 e2 = *(const uint4*)&ex[rbB + 8];
    __syncthreads();  // all reads done before anyone overwrites
    const hf2* tb = Thp + ((size_t)l * 32 + 4 * ws) * 48;
    float zA0[3], zA1[3], zA2[3], zA3[3];
    float zB0[3], zB1[3], zB2[3], zB3[3];
    // interleave tiles per-k: each T sub-slice loaded once, used twice
    evalk_sc(tb + 0 * 48, a0.x, a0.y, a0.z, zA0);
    evalk_sc(tb + 0 * 48, e0.x, e0.y, e0.z, zB0);
    evalk_sc(tb + 1 * 48, a0.w, a1.x, a1.y, zA1);
    evalk_sc(tb + 1 * 48, e0.w, e1.x, e1.y, zB1);
    evalk_sc(tb + 2 * 48, a1.z, a1.w, a2.x, zA2);
    evalk_sc(tb + 2 * 48, e1.z, e1.w, e2.x, zB2);
    evalk_sc(tb + 3 * 48, a2.y, a2.z, a2.w, zA3);
    evalk_sc(tb + 3 * 48, e2.y, e2.z, e2.w, zB3);
    if (l == 0) {
#pragma unroll
      for (int j = 0; j < 3; ++j) {
        hA[0][j] = zA0[j]; hA[1][j] = zA1[j]; hA[2][j] = zA2[j]; hA[3][j] = zA3[j];
        hB[0][j] = zB0[j]; hB[1][j] = zB1[j]; hB[2][j] = zB2[j]; hB[3][j] = zB3[j];
      }
    } else {
#pragma unroll
      for (int j = 0; j < 3; ++j) {
        hA[0][j] += zA0[j]; hA[1][j] += zA1[j]; hA[2][j] += zA2[j]; hA[3][j] += zA3[j];
        hB[0][j] += zB0[j]; hB[1][j] += zB1[j]; hB[2][j] += zB2[j]; hB[3][j] += zB3[j];
      }
    }
    if (l < 4) {
      // writer does sincos+pack; S[32j+4ws+i] = (s,c) of h[i][j], both tiles
#pragma unroll
      for (int j = 0; j < 3; ++j) {
        uint4 wv;
        wv.x = pk_sc(hA[0][j]);
        wv.y = pk_sc(hA[1][j]);
        wv.z = pk_sc(hA[2][j]);
        wv.w = pk_sc(hA[3][j]);
        *(uint4*)&ex[b * 100 + 32 * j + 4 * ws] = wv;
        uint4 wv2;
        wv2.x = pk_sc(hB[0][j]);
        wv2.y = pk_sc(hB[1][j]);
        wv2.z = pk_sc(hB[2][j]);
        wv2.w = pk_sc(hB[3][j]);
        *(uint4*)&ex[(64 + b) * 100 + 32 * j + 4 * ws] = wv2;
      }
      __syncthreads();  // writes visible before next layer's reads
    }
  }

  // layer 5 (reduce, wire 0): inputs = own regs; stash z (f32) at slots [row][k]
  {
    float4 zv;
    zv.x = evalk1(T5 + (4 * ws + 0) * 16, hA[0][0], hA[0][1], hA[0][2]);
    zv.y = evalk1(T5 + (4 * ws + 1) * 16, hA[1][0], hA[1][1], hA[1][2]);
    zv.z = evalk1(T5 + (4 * ws + 2) * 16, hA[2][0], hA[2][1], hA[2][2]);
    zv.w = evalk1(T5 + (4 * ws + 3) * 16, hA[3][0], hA[3][1], hA[3][2]);
    *(float4*)&ex[b * 100 + 4 * ws] = zv;
    float4 zv2;
    zv2.x = evalk1(T5 + (4 * ws + 0) * 16, hB[0][0], hB[0][1], hB[0][2]);
    zv2.y = evalk1(T5 + (4 * ws + 1) * 16, hB[1][0], hB[1][1], hB[1][2]);
    zv2.z = evalk1(T5 + (4 * ws + 2) * 16, hB[2][0], hB[2][1], hB[2][2]);
    zv2.w = evalk1(T5 + (4 * ws + 3) * 16, hB[3][0], hB[3][1], hB[3][2]);
    *(float4*)&ex[(64 + b) * 100 + 4 * ws] = zv2;
  }
  __syncthreads();

  // classifier: out[row][c] = sum_k z[row][k] * wcls[c][k] + bcls[c]
  for (int idx = t; idx < 1280; idx += 512) {
    int bb = idx / 10, c = idx % 10;
    float acc = bcls[c];
#pragma unroll
    for (int k = 0; k < 32; ++k)
      acc = fmaf(__uint_as_float(ex[bb * 100 + k]), wcls[c * 32 + k], acc);
    out[(b0 + bb) * 10 + c] = acc;
  }
}

extern "C" void kernel_launch(void* const* d_in, const int* in_sizes, int n_in,
                              void* d_out, int out_size, void* d_ws, size_t ws_size,
                              hipStream_t stream) {
  const float* x  = (const float*)d_in[0];   // (65536, 96) f32
  const float* th = (const float*)d_in[1];   // (6,32,6,3,3) f32
  const float* wc = (const float*)d_in[2];   // (10,32) f32
  const float* bc = (const float*)d_in[3];   // (10,) f32
  float* out = (float*)d_out;                // (65536,10) f32
  hf2* Thp = (hf2*)d_ws;                     // 5*32*48 hf2 (30.7 KB), 1/2pi-scaled
  hf2* T5  = Thp + 5 * 32 * 48;              // 32*16 hf2 (2 KB), unscaled

  build_T<<<192, 64, 0, stream>>>(th, Thp, T5);
  vqc_main<<<65536 / 128, 512, 0, stream>>>(x, Thp, T5, wc, bc, out);
}